// Round 8
// baseline (177.398 us; speedup 1.0000x reference)
//
#include <hip/hip_runtime.h>

typedef __attribute__((ext_vector_type(8))) _Float16 f16x8;
typedef __attribute__((ext_vector_type(4))) _Float16 f16x4;
typedef __attribute__((ext_vector_type(4))) float f32x4;

constexpr int B_ = 128, N_ = 32, D_ = 256, H_ = 1024;
constexpr int XPAD  = 260;   // f32 X row stride in LDS
constexpr int SROW  = 1032;  // f16 row stride of s16 tile (2064 B)
constexpr int XJROW = 264;   // f16 row stride of xj16 table

// LDS map (bytes):
//  [0,     33280)  Xs f32 [32][260] (prologue overlay)
//                  -> after sync2: s16 f16 [16][1032] = 33024 B (aliases dead Xs)
//  [33280, 41728)  xj16 f16 [16][264]  (f16 copies of the block's 16 j-rows)
//  [41728, 45824)  b1s f32 [1024]
constexpr int LDS_MAIN = 45824;

// ---------------------------------------------------------------------------
// prep2: coalesced 32x32 LDS-tile transposes + f32->f16 cast.
//  W1T[h][k] = f16(W1[k][h])   (W1 [256][1024] -> W1T [1024][256])
//  W2T[d][h] = f16(W2[h][d])   (W2 [1024][256] -> W2T [256][1024])
// ---------------------------------------------------------------------------
__global__ void prep2(const float* __restrict__ W1, const float* __restrict__ W2,
                      _Float16* __restrict__ W1T, _Float16* __restrict__ W2T) {
    __shared__ float tile[32][36];
    const int t = threadIdx.x;
    const int r = t >> 3, cq = (t & 7) * 4;
    int bb = blockIdx.x;
    if (bb < 256) {
        int tk = bb >> 5, th = bb & 31; // k-tile, h-tile
        *(f32x4*)&tile[r][cq] = *(const f32x4*)(W1 + (size_t)(tk * 32 + r) * 1024 + th * 32 + cq);
        __syncthreads();
        f16x4 o;
        #pragma unroll
        for (int q = 0; q < 4; ++q) o[q] = (_Float16)tile[cq + q][r];
        *(f16x4*)(W1T + (size_t)(th * 32 + r) * 256 + tk * 32 + cq) = o;
    } else {
        bb -= 256;
        int th = bb >> 3, td = bb & 7;  // h-tile, d-tile
        *(f32x4*)&tile[r][cq] = *(const f32x4*)(W2 + (size_t)(th * 32 + r) * 256 + td * 32 + cq);
        __syncthreads();
        f16x4 o;
        #pragma unroll
        for (int q = 0; q < 4; ++q) o[q] = (_Float16)tile[cq + q][r];
        *(f16x4*)(W2T + (size_t)(td * 32 + r) * 1024 + th * 32 + cq) = o;
    }
}

// ---------------------------------------------------------------------------
// main (weights-stationary, fused): grid = B * 2 = 256 blocks (1/CU),
// 512 threads (8 waves). Block owns (b, 16 j's, all 1024 h).
// Wave w owns h-cols [hg*512 + w*64, +64) per hg-iteration (hg = 0,1):
//   - W1 B-fragments for 64 h x K=256 held in 128 VGPRs (loaded once per hg
//     from L2-resident W1T; no LDS staging, no barriers in the j-loop).
//   - xi16 (X rows as f16 A-operand parts) held in 64 VGPRs.
//   - per j: A-frags P = xi16 * xj16 (v_pk_mul_f16), 64 MFMAs, epilogue
//     relu+row-sum (4 reg-adds + 2 shfl), f16 write to s16[j][h].
// Tail: fused layer-2, M=16 (all j rows valid):
//   out[j][d] = s16[j][:] @ W2T[d][:] + 32*b2[d].
// ---------------------------------------------------------------------------
__global__ __launch_bounds__(512, 2)
void interaction_main(const float* __restrict__ Xg, const float* __restrict__ b1g,
                      const float* __restrict__ b2g, const _Float16* __restrict__ W1T,
                      const _Float16* __restrict__ W2T, float* __restrict__ outg) {
    __shared__ __align__(16) unsigned char smem[LDS_MAIN];

    const int tid = threadIdx.x;
    const int w = tid >> 6, l = tid & 63, l15 = l & 15, lg = l >> 4;
    const int bid = blockIdx.x;
    const int b = bid >> 1, jg = bid & 1;
    const int j0 = jg * 16;

    float*     Xs   = (float*)smem;               // overlay (dies at sync2)
    _Float16*  s16  = (_Float16*)smem;            // aliases Xs after sync2
    _Float16*  xj16 = (_Float16*)(smem + 33280);
    float*     b1s  = (float*)(smem + 41728);

    // ---- prologue: X_b -> LDS (padded f32), b1 -> LDS ----
    {
        const float* xb = Xg + (size_t)b * (N_ * D_);
        int row = tid >> 4, c0 = (tid & 15) * 16;
        #pragma unroll
        for (int q = 0; q < 4; ++q)
            *(f32x4*)(Xs + row * XPAD + c0 + q * 4) = *(const f32x4*)(xb + row * 256 + c0 + q * 4);
        b1s[tid]       = b1g[tid];
        b1s[tid + 512] = b1g[tid + 512];
    }
    __syncthreads();

    // ---- xj16 table: f16 copies of the block's 16 j-rows ----
    {
        int row = tid >> 5, c8 = (tid & 31) * 8;
        const float* src = Xs + (j0 + row) * XPAD + c8;
        f16x8 o;
        #pragma unroll
        for (int q = 0; q < 8; ++q) o[q] = (_Float16)src[q];
        *(f16x8*)(xj16 + row * XJROW + c8) = o;
    }

    // ---- xi16 regs: X[i][k] as f16, i = nt*16 + l15, k = ks*32 + lg*8 + q ----
    f16x8 xi16[2][8];
    #pragma unroll
    for (int nt = 0; nt < 2; ++nt)
        #pragma unroll
        for (int ks = 0; ks < 8; ++ks) {
            const float* src = Xs + (nt * 16 + l15) * XPAD + ks * 32 + lg * 8;
            f16x8 o;
            #pragma unroll
            for (int q = 0; q < 8; ++q) o[q] = (_Float16)src[q];
            xi16[nt][ks] = o;
        }
    __syncthreads(); // xj16 ready; all X reads done -> s16 region free

    // ---- main: hg x j loops, barrier-free ----
    for (int hg = 0; hg < 2; ++hg) {
        const int hbase = hg * 512 + w * 64;

        // W1 B-fragments: col h = l15 within ct-tile, k = ks*32 + lg*8 + q
        f16x8 w1f[4][8];
        #pragma unroll
        for (int ct = 0; ct < 4; ++ct) {
            const _Float16* wp = W1T + (size_t)(hbase + ct * 16 + l15) * 256 + lg * 8;
            #pragma unroll
            for (int ks = 0; ks < 8; ++ks)
                w1f[ct][ks] = *(const f16x8*)(wp + ks * 32);
        }
        float b1v[4];
        #pragma unroll
        for (int ct = 0; ct < 4; ++ct) b1v[ct] = b1s[hbase + ct * 16 + l15];

        for (int j = 0; j < 16; ++j) {
            const _Float16* xjp = xj16 + j * XJROW + lg * 8;
            f32x4 acc[2][4] = {}; // [nt][ct], D[i16][h16]
            #pragma unroll
            for (int ks = 0; ks < 8; ++ks) {
                f16x8 xjf = *(const f16x8*)(xjp + ks * 32); // broadcast read
                f16x8 p0 = xi16[0][ks] * xjf;               // v_pk_mul_f16
                f16x8 p1 = xi16[1][ks] * xjf;
                #pragma unroll
                for (int ct = 0; ct < 4; ++ct) {
                    acc[0][ct] = __builtin_amdgcn_mfma_f32_16x16x32_f16(p0, w1f[ct][ks], acc[0][ct], 0, 0, 0);
                    acc[1][ct] = __builtin_amdgcn_mfma_f32_16x16x32_f16(p1, w1f[ct][ks], acc[1][ct], 0, 0, 0);
                }
            }
            // epilogue: +b1, ReLU, sum over 32 i (4 regs x 2 nt + lanes^16,^32)
            #pragma unroll
            for (int ct = 0; ct < 4; ++ct) {
                float v = 0.f;
                #pragma unroll
                for (int nt = 0; nt < 2; ++nt)
                    #pragma unroll
                    for (int r = 0; r < 4; ++r)
                        v += fmaxf(acc[nt][ct][r] + b1v[ct], 0.f);
                v += __shfl_xor(v, 16, 64);
                v += __shfl_xor(v, 32, 64);
                if (l < 16) s16[j * SROW + hbase + ct * 16 + l15] = (_Float16)v;
            }
        }
    }
    __syncthreads(); // s16 complete & visible

    // ---- fused layer 2: out[j][d] = s16[j][:] @ W2T[d][:] + 32*b2[d] ----
    // A rows = 16 j (all valid); wave w owns d in [w*32, w*32+32) (2 ct-tiles).
    f32x4 acc2[2] = {};
    const _Float16* ap  = s16 + l15 * SROW + lg * 8;
    const _Float16* bp0 = W2T + (size_t)(w * 32 + l15) * 1024 + lg * 8;
    const _Float16* bp1 = bp0 + 16 * 1024;
    #pragma unroll 8
    for (int ks = 0; ks < 32; ++ks) {
        f16x8 af = *(const f16x8*)(ap + ks * 32);
        acc2[0] = __builtin_amdgcn_mfma_f32_16x16x32_f16(af, *(const f16x8*)(bp0 + ks * 32), acc2[0], 0, 0, 0);
        acc2[1] = __builtin_amdgcn_mfma_f32_16x16x32_f16(af, *(const f16x8*)(bp1 + ks * 32), acc2[1], 0, 0, 0);
    }
    #pragma unroll
    for (int t2 = 0; t2 < 2; ++t2) {
        int d = w * 32 + t2 * 16 + l15;
        float bb = 32.f * b2g[d];
        #pragma unroll
        for (int r = 0; r < 4; ++r) {
            int jloc = lg * 4 + r; // D row = j-local
            outg[(size_t)(b * 32 + j0 + jloc) * 256 + d] = acc2[t2][r] + bb;
        }
    }
}

// ---------------------------------------------------------------------------
extern "C" void kernel_launch(void* const* d_in, const int* in_sizes, int n_in,
                              void* d_out, int out_size, void* d_ws, size_t ws_size,
                              hipStream_t stream) {
    const float* X  = (const float*)d_in[0]; // [128,32,256]
    const float* W1 = (const float*)d_in[1]; // [256,1024]
    const float* b1 = (const float*)d_in[2]; // [1024]
    const float* W2 = (const float*)d_in[3]; // [1024,256]
    const float* b2 = (const float*)d_in[4]; // [256]
    float* out = (float*)d_out;              // [128,32,256]

    _Float16* W1T = (_Float16*)d_ws;         // [1024][256]  512 KB
    _Float16* W2T = W1T + 262144;            // [256][1024]  512 KB

    prep2<<<dim3(512), dim3(256), 0, stream>>>(W1, W2, W1T, W2T);
    interaction_main<<<dim3(B_ * 2), dim3(512), 0, stream>>>(X, b1, b2, W1T, W2T, out);
}

// Round 9
// 150.113 us; speedup vs baseline: 1.1818x; 1.1818x over previous
//
#include <hip/hip_runtime.h>

typedef __attribute__((ext_vector_type(8))) _Float16 f16x8;
typedef __attribute__((ext_vector_type(4))) _Float16 f16x4;
typedef __attribute__((ext_vector_type(4))) float f32x4;

constexpr int B_ = 128, N_ = 32, D_ = 256, H_ = 1024;
constexpr int XPAD  = 260;   // f32 X row stride in LDS
constexpr int SROW  = 1032;  // f16 row stride of s16 tile (2064 B)
constexpr int XJROW = 264;   // f16 row stride of xj16 table

// LDS map (bytes):
//  [0,     33280)  Xs f32 [32][260] (prologue overlay)
//                  -> after sync2: s16 f16 [16][1032] = 33024 B (aliases dead Xs)
//  [33280, 41728)  xj16 f16 [16][264]  (f16 copies of the block's 16 j-rows)
//  [41728, 45824)  b1s f32 [1024]
constexpr int LDS_MAIN = 45824;

// ---------------------------------------------------------------------------
// prep2: coalesced 32x32 LDS-tile transposes + f32->f16 cast.
//  W1T[h][k] = f16(W1[k][h])   (W1 [256][1024] -> W1T [1024][256])
//  W2T[d][h] = f16(W2[h][d])   (W2 [1024][256] -> W2T [256][1024])
// ---------------------------------------------------------------------------
__global__ void prep2(const float* __restrict__ W1, const float* __restrict__ W2,
                      _Float16* __restrict__ W1T, _Float16* __restrict__ W2T) {
    __shared__ float tile[32][36];
    const int t = threadIdx.x;
    const int r = t >> 3, cq = (t & 7) * 4;
    int bb = blockIdx.x;
    if (bb < 256) {
        int tk = bb >> 5, th = bb & 31; // k-tile, h-tile
        *(f32x4*)&tile[r][cq] = *(const f32x4*)(W1 + (size_t)(tk * 32 + r) * 1024 + th * 32 + cq);
        __syncthreads();
        f16x4 o;
        #pragma unroll
        for (int q = 0; q < 4; ++q) o[q] = (_Float16)tile[cq + q][r];
        *(f16x4*)(W1T + (size_t)(th * 32 + r) * 256 + tk * 32 + cq) = o;
    } else {
        bb -= 256;
        int th = bb >> 3, td = bb & 7;  // h-tile, d-tile
        *(f32x4*)&tile[r][cq] = *(const f32x4*)(W2 + (size_t)(th * 32 + r) * 256 + td * 32 + cq);
        __syncthreads();
        f16x4 o;
        #pragma unroll
        for (int q = 0; q < 4; ++q) o[q] = (_Float16)tile[cq + q][r];
        *(f16x4*)(W2T + (size_t)(td * 32 + r) * 1024 + th * 32 + cq) = o;
    }
}

// ---------------------------------------------------------------------------
// main (weights-stationary, fused): grid = B * 2 = 256 blocks (1/CU),
// 512 threads (8 waves). Block owns (b, 16 j's, all 1024 h).
// Wave w owns h-cols [hg*256 + w*32, +32) per hg-pass (hg = 0..3):
//   - W1 B-fragments for 32 h x K=256 in 64 VGPRs, loaded once per pass
//     from L2-resident W1T (no LDS staging, no spills: ~175 regs total).
//   - xi16 (X rows as f16 A-parts) in 64 VGPRs.
//   - per j: A-frags P = xi16 * xj16 (v_pk_mul_f16), 32 MFMAs, epilogue
//     relu+row-sum (shfl 16/32), f16 write to s16[j][h]. Barrier-free.
// Tail: fused layer-2, M=16: out[j][d] = s16[j][:] @ W2T[d][:] + 32*b2[d].
// ---------------------------------------------------------------------------
__global__ __launch_bounds__(512, 2)
void interaction_main(const float* __restrict__ Xg, const float* __restrict__ b1g,
                      const float* __restrict__ b2g, const _Float16* __restrict__ W1T,
                      const _Float16* __restrict__ W2T, float* __restrict__ outg) {
    __shared__ __align__(16) unsigned char smem[LDS_MAIN];

    const int tid = threadIdx.x;
    const int w = tid >> 6, l = tid & 63, l15 = l & 15, lg = l >> 4;
    const int bid = blockIdx.x;
    const int b = bid >> 1, jg = bid & 1;
    const int j0 = jg * 16;

    float*     Xs   = (float*)smem;               // overlay (dies at sync2)
    _Float16*  s16  = (_Float16*)smem;            // aliases Xs after sync2
    _Float16*  xj16 = (_Float16*)(smem + 33280);
    float*     b1s  = (float*)(smem + 41728);

    // ---- prologue: X_b -> LDS (padded f32), b1 -> LDS ----
    {
        const float* xb = Xg + (size_t)b * (N_ * D_);
        int row = tid >> 4, c0 = (tid & 15) * 16;
        #pragma unroll
        for (int q = 0; q < 4; ++q)
            *(f32x4*)(Xs + row * XPAD + c0 + q * 4) = *(const f32x4*)(xb + row * 256 + c0 + q * 4);
        b1s[tid]       = b1g[tid];
        b1s[tid + 512] = b1g[tid + 512];
    }
    __syncthreads();

    // ---- xj16 table: f16 copies of the block's 16 j-rows ----
    {
        int row = tid >> 5, c8 = (tid & 31) * 8;
        const float* src = Xs + (j0 + row) * XPAD + c8;
        f16x8 o;
        #pragma unroll
        for (int q = 0; q < 8; ++q) o[q] = (_Float16)src[q];
        *(f16x8*)(xj16 + row * XJROW + c8) = o;
    }

    // ---- xi16 regs: X[i][k] as f16, i = nt*16 + l15, k = ks*32 + lg*8 + q ----
    f16x8 xi16[2][8];
    #pragma unroll
    for (int nt = 0; nt < 2; ++nt)
        #pragma unroll
        for (int ks = 0; ks < 8; ++ks) {
            const float* src = Xs + (nt * 16 + l15) * XPAD + ks * 32 + lg * 8;
            f16x8 o;
            #pragma unroll
            for (int q = 0; q < 8; ++q) o[q] = (_Float16)src[q];
            xi16[nt][ks] = o;
        }
    __syncthreads(); // xj16 ready; all X reads done -> s16 region free

    // ---- main: hg x j loops, barrier-free ----
    for (int hg = 0; hg < 4; ++hg) {
        const int hbase = hg * 256 + w * 32;

        // W1 B-fragments: col h = l15 within ct-tile, k = ks*32 + lg*8 + q
        f16x8 w1f[2][8];
        #pragma unroll
        for (int ct = 0; ct < 2; ++ct) {
            const _Float16* wp = W1T + (size_t)(hbase + ct * 16 + l15) * 256 + lg * 8;
            #pragma unroll
            for (int ks = 0; ks < 8; ++ks)
                w1f[ct][ks] = *(const f16x8*)(wp + ks * 32);
        }
        float b1v[2];
        #pragma unroll
        for (int ct = 0; ct < 2; ++ct) b1v[ct] = b1s[hbase + ct * 16 + l15];

        for (int j = 0; j < 16; ++j) {
            const _Float16* xjp = xj16 + j * XJROW + lg * 8;
            f32x4 acc[2][2] = {}; // [nt][ct], D[i16][h16]
            #pragma unroll
            for (int ks = 0; ks < 8; ++ks) {
                f16x8 xjf = *(const f16x8*)(xjp + ks * 32); // broadcast read
                f16x8 p0 = xi16[0][ks] * xjf;               // v_pk_mul_f16
                f16x8 p1 = xi16[1][ks] * xjf;
                #pragma unroll
                for (int ct = 0; ct < 2; ++ct) {
                    acc[0][ct] = __builtin_amdgcn_mfma_f32_16x16x32_f16(p0, w1f[ct][ks], acc[0][ct], 0, 0, 0);
                    acc[1][ct] = __builtin_amdgcn_mfma_f32_16x16x32_f16(p1, w1f[ct][ks], acc[1][ct], 0, 0, 0);
                }
            }
            // epilogue: +b1, ReLU, sum over 32 i (8 reg-adds + lanes^16,^32)
            #pragma unroll
            for (int ct = 0; ct < 2; ++ct) {
                float v = 0.f;
                #pragma unroll
                for (int nt = 0; nt < 2; ++nt)
                    #pragma unroll
                    for (int r = 0; r < 4; ++r)
                        v += fmaxf(acc[nt][ct][r] + b1v[ct], 0.f);
                v += __shfl_xor(v, 16, 64);
                v += __shfl_xor(v, 32, 64);
                if (l < 16) s16[j * SROW + hbase + ct * 16 + l15] = (_Float16)v;
            }
        }
    }
    __syncthreads(); // s16 complete & visible

    // ---- fused layer 2: out[j][d] = s16[j][:] @ W2T[d][:] + 32*b2[d] ----
    // A rows = 16 j (all valid); wave w owns d in [w*32, w*32+32) (2 ct-tiles).
    f32x4 acc2[2] = {};
    const _Float16* ap  = s16 + l15 * SROW + lg * 8;
    const _Float16* bp0 = W2T + (size_t)(w * 32 + l15) * 1024 + lg * 8;
    const _Float16* bp1 = bp0 + 16 * 1024;
    #pragma unroll 8
    for (int ks = 0; ks < 32; ++ks) {
        f16x8 af = *(const f16x8*)(ap + ks * 32);
        acc2[0] = __builtin_amdgcn_mfma_f32_16x16x32_f16(af, *(const f16x8*)(bp0 + ks * 32), acc2[0], 0, 0, 0);
        acc2[1] = __builtin_amdgcn_mfma_f32_16x16x32_f16(af, *(const f16x8*)(bp1 + ks * 32), acc2[1], 0, 0, 0);
    }
    #pragma unroll
    for (int t2 = 0; t2 < 2; ++t2) {
        int d = w * 32 + t2 * 16 + l15;
        float bb = 32.f * b2g[d];
        #pragma unroll
        for (int r = 0; r < 4; ++r) {
            int jloc = lg * 4 + r; // D row = j-local
            outg[(size_t)(b * 32 + j0 + jloc) * 256 + d] = acc2[t2][r] + bb;
        }
    }
}

// ---------------------------------------------------------------------------
extern "C" void kernel_launch(void* const* d_in, const int* in_sizes, int n_in,
                              void* d_out, int out_size, void* d_ws, size_t ws_size,
                              hipStream_t stream) {
    const float* X  = (const float*)d_in[0]; // [128,32,256]
    const float* W1 = (const float*)d_in[1]; // [256,1024]
    const float* b1 = (const float*)d_in[2]; // [1024]
    const float* W2 = (const float*)d_in[3]; // [1024,256]
    const float* b2 = (const float*)d_in[4]; // [256]
    float* out = (float*)d_out;              // [128,32,256]

    _Float16* W1T = (_Float16*)d_ws;         // [1024][256]  512 KB
    _Float16* W2T = W1T + 262144;            // [256][1024]  512 KB

    prep2<<<dim3(512), dim3(256), 0, stream>>>(W1, W2, W1T, W2T);
    interaction_main<<<dim3(B_ * 2), dim3(512), 0, stream>>>(X, b1, b2, W1T, W2T, out);
}

// Round 10
// 149.240 us; speedup vs baseline: 1.1887x; 1.0059x over previous
//
#include <hip/hip_runtime.h>

typedef __attribute__((ext_vector_type(8))) _Float16 f16x8;
typedef __attribute__((ext_vector_type(4))) _Float16 f16x4;
typedef __attribute__((ext_vector_type(4))) float f32x4;

constexpr int B_ = 128, N_ = 32, D_ = 256, H_ = 1024;
constexpr int XPAD  = 260;   // f32 X row stride in LDS
constexpr int SROW  = 1032;  // f16 row stride of s16 tile (2064 B)
constexpr int XJROW = 264;   // f16 row stride of xj16 table

// LDS map (bytes):
//  [0,     33280)  Xs f32 [32][260] (prologue overlay)
//                  -> after sync2: s16 f16 [16][1032] = 33024 B (aliases dead Xs)
//  [33280, 41728)  xj16 f16 [16][264]  (f16 copies of the block's 16 j-rows)
//  [41728, 45824)  b1s f32 [1024]
constexpr int LDS_MAIN = 45824;

#define MFMA16(A, B, C) __builtin_amdgcn_mfma_f32_16x16x32_f16((A), (B), (C), 0, 0, 0)

// ---------------------------------------------------------------------------
// prep2: coalesced 32x32 LDS-tile transposes + f32->f16 cast.
//  W1T[h][k] = f16(W1[k][h])   (W1 [256][1024] -> W1T [1024][256])
//  W2T[d][h] = f16(W2[h][d])   (W2 [1024][256] -> W2T [256][1024])
// ---------------------------------------------------------------------------
__global__ void prep2(const float* __restrict__ W1, const float* __restrict__ W2,
                      _Float16* __restrict__ W1T, _Float16* __restrict__ W2T) {
    __shared__ float tile[32][36];
    const int t = threadIdx.x;
    const int r = t >> 3, cq = (t & 7) * 4;
    int bb = blockIdx.x;
    if (bb < 256) {
        int tk = bb >> 5, th = bb & 31; // k-tile, h-tile
        *(f32x4*)&tile[r][cq] = *(const f32x4*)(W1 + (size_t)(tk * 32 + r) * 1024 + th * 32 + cq);
        __syncthreads();
        f16x4 o;
        #pragma unroll
        for (int q = 0; q < 4; ++q) o[q] = (_Float16)tile[cq + q][r];
        *(f16x4*)(W1T + (size_t)(th * 32 + r) * 256 + tk * 32 + cq) = o;
    } else {
        bb -= 256;
        int th = bb >> 3, td = bb & 7;  // h-tile, d-tile
        *(f32x4*)&tile[r][cq] = *(const f32x4*)(W2 + (size_t)(th * 32 + r) * 256 + td * 32 + cq);
        __syncthreads();
        f16x4 o;
        #pragma unroll
        for (int q = 0; q < 4; ++q) o[q] = (_Float16)tile[cq + q][r];
        *(f16x4*)(W2T + (size_t)(td * 32 + r) * 1024 + th * 32 + cq) = o;
    }
}

// ---------------------------------------------------------------------------
// main (weights-stationary, fused): grid = B * 2 = 256 blocks (1/CU),
// 512 threads (8 waves). Block owns (b, 16 j's, all 1024 h).
// Wave w owns h-cols [hg*256 + w*32, +32) per hg-pass (hg = 0..3):
//   - W1 B-fragments for 32 h x K=256 in 64 VGPRs, loaded once per pass and
//     PINNED via asm def-barrier (compiler may not re-load them in the j-loop
//     -- R9's VGPR_Count=88 proved it sank these loads, making the loop
//     L2-bound).
//   - xi16 (X rows as f16 A-parts) in 64 VGPRs.
//   - j's processed in PAIRS (2 independent MFMA chains + overlapped
//     epilogues) with ks-depth-1 xjf prefetch: LDS latency and epilogue
//     VALU hide under the 64-MFMA burst. Barrier-free.
// Tail: fused layer-2, M=16: out[j][d] = s16[j][:] @ W2T[d][:] + 32*b2[d].
// ---------------------------------------------------------------------------
__global__ __launch_bounds__(512, 2)
void interaction_main(const float* __restrict__ Xg, const float* __restrict__ b1g,
                      const float* __restrict__ b2g, const _Float16* __restrict__ W1T,
                      const _Float16* __restrict__ W2T, float* __restrict__ outg) {
    __shared__ __align__(16) unsigned char smem[LDS_MAIN];

    const int tid = threadIdx.x;
    const int w = tid >> 6, l = tid & 63, l15 = l & 15, lg = l >> 4;
    const int bid = blockIdx.x;
    const int b = bid >> 1, jg = bid & 1;
    const int j0 = jg * 16;

    float*     Xs   = (float*)smem;               // overlay (dies at sync2)
    _Float16*  s16  = (_Float16*)smem;            // aliases Xs after sync2
    _Float16*  xj16 = (_Float16*)(smem + 33280);
    float*     b1s  = (float*)(smem + 41728);

    // ---- prologue: X_b -> LDS (padded f32), b1 -> LDS ----
    {
        const float* xb = Xg + (size_t)b * (N_ * D_);
        int row = tid >> 4, c0 = (tid & 15) * 16;
        #pragma unroll
        for (int q = 0; q < 4; ++q)
            *(f32x4*)(Xs + row * XPAD + c0 + q * 4) = *(const f32x4*)(xb + row * 256 + c0 + q * 4);
        b1s[tid]       = b1g[tid];
        b1s[tid + 512] = b1g[tid + 512];
    }
    __syncthreads();

    // ---- xj16 table: f16 copies of the block's 16 j-rows ----
    {
        int row = tid >> 5, c8 = (tid & 31) * 8;
        const float* src = Xs + (j0 + row) * XPAD + c8;
        f16x8 o;
        #pragma unroll
        for (int q = 0; q < 8; ++q) o[q] = (_Float16)src[q];
        *(f16x8*)(xj16 + row * XJROW + c8) = o;
    }

    // ---- xi16 regs: X[i][k] as f16, i = nt*16 + l15, k = ks*32 + lg*8 + q ----
    f16x8 xi16[2][8];
    #pragma unroll
    for (int nt = 0; nt < 2; ++nt)
        #pragma unroll
        for (int ks = 0; ks < 8; ++ks) {
            const float* src = Xs + (nt * 16 + l15) * XPAD + ks * 32 + lg * 8;
            f16x8 o;
            #pragma unroll
            for (int q = 0; q < 8; ++q) o[q] = (_Float16)src[q];
            xi16[nt][ks] = o;
        }
    __syncthreads(); // xj16 ready; all X reads done -> s16 region free

    // ---- main: hg x j-pair loops, barrier-free ----
    for (int hg = 0; hg < 4; ++hg) {
        const int hbase = hg * 256 + w * 32;

        // W1 B-fragments: col h = l15 within ct-tile, k = ks*32 + lg*8 + q
        f16x8 w1f[2][8];
        #pragma unroll
        for (int ct = 0; ct < 2; ++ct) {
            const _Float16* wp = W1T + (size_t)(hbase + ct * 16 + l15) * 256 + lg * 8;
            #pragma unroll
            for (int ks = 0; ks < 8; ++ks) {
                w1f[ct][ks] = *(const f16x8*)(wp + ks * 32);
                asm volatile("" : "+v"(w1f[ct][ks])); // pin: forbid re-load in j-loop
            }
        }
        float b1v[2];
        #pragma unroll
        for (int ct = 0; ct < 2; ++ct) b1v[ct] = b1s[hbase + ct * 16 + l15];

        for (int jp = 0; jp < 8; ++jp) {
            const int j = jp * 2;
            const _Float16* xjpA = xj16 + j * XJROW + lg * 8;
            const _Float16* xjpB = xjpA + XJROW;
            f32x4 accA[2][2] = {}; // [nt][ct]
            f32x4 accB[2][2] = {};
            f16x8 xaN = *(const f16x8*)(xjpA);
            f16x8 xbN = *(const f16x8*)(xjpB);
            __builtin_amdgcn_s_setprio(1);
            #pragma unroll
            for (int ks = 0; ks < 8; ++ks) {
                f16x8 xaC = xaN, xbC = xbN;
                if (ks < 7) {
                    xaN = *(const f16x8*)(xjpA + (ks + 1) * 32); // prefetch next ks
                    xbN = *(const f16x8*)(xjpB + (ks + 1) * 32);
                }
                f16x8 pa0 = xi16[0][ks] * xaC;  // v_pk_mul_f16
                f16x8 pa1 = xi16[1][ks] * xaC;
                accA[0][0] = MFMA16(pa0, w1f[0][ks], accA[0][0]);
                accA[0][1] = MFMA16(pa0, w1f[1][ks], accA[0][1]);
                accA[1][0] = MFMA16(pa1, w1f[0][ks], accA[1][0]);
                accA[1][1] = MFMA16(pa1, w1f[1][ks], accA[1][1]);
                f16x8 pb0 = xi16[0][ks] * xbC;
                f16x8 pb1 = xi16[1][ks] * xbC;
                accB[0][0] = MFMA16(pb0, w1f[0][ks], accB[0][0]);
                accB[0][1] = MFMA16(pb0, w1f[1][ks], accB[0][1]);
                accB[1][0] = MFMA16(pb1, w1f[0][ks], accB[1][0]);
                accB[1][1] = MFMA16(pb1, w1f[1][ks], accB[1][1]);
            }
            __builtin_amdgcn_s_setprio(0);

            // epilogue (both j's): +b1, ReLU, sum over 32 i, f16 write to s16
            #pragma unroll
            for (int ct = 0; ct < 2; ++ct) {
                float vA = 0.f, vB = 0.f;
                #pragma unroll
                for (int nt = 0; nt < 2; ++nt)
                    #pragma unroll
                    for (int r = 0; r < 4; ++r) {
                        vA += fmaxf(accA[nt][ct][r] + b1v[ct], 0.f);
                        vB += fmaxf(accB[nt][ct][r] + b1v[ct], 0.f);
                    }
                vA += __shfl_xor(vA, 16, 64);
                vA += __shfl_xor(vA, 32, 64);
                vB += __shfl_xor(vB, 16, 64);
                vB += __shfl_xor(vB, 32, 64);
                if (l < 16) {
                    int hcol = hbase + ct * 16 + l15;
                    s16[j * SROW + hcol]       = (_Float16)vA;
                    s16[(j + 1) * SROW + hcol] = (_Float16)vB;
                }
            }
        }
    }
    __syncthreads(); // s16 complete & visible

    // ---- fused layer 2: out[j][d] = s16[j][:] @ W2T[d][:] + 32*b2[d] ----
    // A rows = 16 j (all valid); wave w owns d in [w*32, w*32+32) (2 ct-tiles).
    f32x4 acc2[2] = {};
    const _Float16* ap  = s16 + l15 * SROW + lg * 8;
    const _Float16* bp0 = W2T + (size_t)(w * 32 + l15) * 1024 + lg * 8;
    const _Float16* bp1 = bp0 + 16 * 1024;
    #pragma unroll 8
    for (int ks = 0; ks < 32; ++ks) {
        f16x8 af = *(const f16x8*)(ap + ks * 32);
        acc2[0] = MFMA16(af, *(const f16x8*)(bp0 + ks * 32), acc2[0]);
        acc2[1] = MFMA16(af, *(const f16x8*)(bp1 + ks * 32), acc2[1]);
    }
    #pragma unroll
    for (int t2 = 0; t2 < 2; ++t2) {
        int d = w * 32 + t2 * 16 + l15;
        float bb = 32.f * b2g[d];
        #pragma unroll
        for (int r = 0; r < 4; ++r) {
            int jloc = lg * 4 + r; // D row = j-local
            outg[(size_t)(b * 32 + j0 + jloc) * 256 + d] = acc2[t2][r] + bb;
        }
    }
}

// ---------------------------------------------------------------------------
extern "C" void kernel_launch(void* const* d_in, const int* in_sizes, int n_in,
                              void* d_out, int out_size, void* d_ws, size_t ws_size,
                              hipStream_t stream) {
    const float* X  = (const float*)d_in[0]; // [128,32,256]
    const float* W1 = (const float*)d_in[1]; // [256,1024]
    const float* b1 = (const float*)d_in[2]; // [1024]
    const float* W2 = (const float*)d_in[3]; // [1024,256]
    const float* b2 = (const float*)d_in[4]; // [256]
    float* out = (float*)d_out;              // [128,32,256]

    _Float16* W1T = (_Float16*)d_ws;         // [1024][256]  512 KB
    _Float16* W2T = W1T + 262144;            // [256][1024]  512 KB

    prep2<<<dim3(512), dim3(256), 0, stream>>>(W1, W2, W1T, W2T);
    interaction_main<<<dim3(B_ * 2), dim3(512), 0, stream>>>(X, b1, b2, W1T, W2T, out);
}